// Round 7
// baseline (99.553 us; speedup 1.0000x reference)
//
#include <hip/hip_runtime.h>

// MLPScorer: out[b,t,s] = sum_d v[d] * tanh( (h_t Wq^T + bq)[b,t,d] + (h_s Wc^T)[b,s,d] )
// B=4, T=S=D=512, all f32.
//
// tanh(x) = 1 - 2/(1+e^{2x});  e^{2(a+u)} = ea*eu (separable; precomputed in the
// GEMM epilogue as exp2(c*...), c = 2*log2(e)).
// Scorer groups 4 consecutive d per output (1 rcp / 4 elements):
//   F_i = fma(ea_i, eu_i, 1);  sum_i v_i/F_i = num/den,
//   num = (v0*F1+v1*F0)*F2*F3 + (v2*F3+v3*F2)*F0*F1, den = F0*F1*F2*F3.
// out = sumv - 2*acc.

#define B_ 4
#define T_ 512
#define S_ 512
#define D_ 512

static constexpr float C2LOG2E = 2.8853900817779268f; // 2*log2(e)

// ---------------------------------------------------------------------------
// Dual GEMM + exp2 epilogue, both jobs Out = X * W^T (K = 512):
//  job0: X=h_t [2048][512], W=Wq  [512][512] -> Ea [2048][512] (+bq), natural layout
//  job1: X=Wc  [512][512],  W=h_s [2048][512] -> Eu4, d-interleaved:
//        Eu4[ ((d>>2)*2048 + col)*4 + (d&3) ], col = b*S+s
// ---------------------------------------------------------------------------
__global__ __launch_bounds__(256) void gemm_exp_kernel(
    const float* __restrict__ Ht, const float* __restrict__ Hs,
    const float* __restrict__ Wq, const float* __restrict__ bq,
    const float* __restrict__ Wc,
    float* __restrict__ Ea, float* __restrict__ Eu4)
{
    __shared__ float Xs[32][68];   // [k][row]
    __shared__ float Ws[32][68];   // [k][col]
    const int job = blockIdx.z;
    const float* __restrict__ X = job ? Wc : Ht;
    const float* __restrict__ W = job ? Hs : Wq;
    const int r0 = (job ? blockIdx.y : blockIdx.x) * 64;   // X-row block
    const int e0 = (job ? blockIdx.x : blockIdx.y) * 64;   // W-row (out col) block

    const int tid = threadIdx.x;
    const int tx  = tid & 15;      // col group (4 cols)
    const int ty  = tid >> 4;      // row group (4 rows)
    const int li  = tid >> 3;          // 0..31 staging row
    const int lk  = (tid & 7) << 2;    // 0,4,...,28 staging k

    float acc[4][4] = {{0.f,0.f,0.f,0.f},{0.f,0.f,0.f,0.f},
                       {0.f,0.f,0.f,0.f},{0.f,0.f,0.f,0.f}};

    for (int k0 = 0; k0 < D_; k0 += 32) {
        const float4 x0 = *(const float4*)(X + (size_t)(r0 + li)      * D_ + k0 + lk);
        const float4 x1 = *(const float4*)(X + (size_t)(r0 + li + 32) * D_ + k0 + lk);
        const float4 w0 = *(const float4*)(W + (size_t)(e0 + li)      * D_ + k0 + lk);
        const float4 w1 = *(const float4*)(W + (size_t)(e0 + li + 32) * D_ + k0 + lk);
        __syncthreads();   // protect previous chunk's LDS reads
        Xs[lk+0][li] = x0.x; Xs[lk+1][li] = x0.y; Xs[lk+2][li] = x0.z; Xs[lk+3][li] = x0.w;
        Xs[lk+0][li+32] = x1.x; Xs[lk+1][li+32] = x1.y; Xs[lk+2][li+32] = x1.z; Xs[lk+3][li+32] = x1.w;
        Ws[lk+0][li] = w0.x; Ws[lk+1][li] = w0.y; Ws[lk+2][li] = w0.z; Ws[lk+3][li] = w0.w;
        Ws[lk+0][li+32] = w1.x; Ws[lk+1][li+32] = w1.y; Ws[lk+2][li+32] = w1.z; Ws[lk+3][li+32] = w1.w;
        __syncthreads();
#pragma unroll
        for (int k = 0; k < 32; ++k) {
            const float4 a  = *(const float4*)&Xs[k][ty << 2];
            const float4 bb = *(const float4*)&Ws[k][tx << 2];
            acc[0][0] = fmaf(a.x, bb.x, acc[0][0]);
            acc[0][1] = fmaf(a.x, bb.y, acc[0][1]);
            acc[0][2] = fmaf(a.x, bb.z, acc[0][2]);
            acc[0][3] = fmaf(a.x, bb.w, acc[0][3]);
            acc[1][0] = fmaf(a.y, bb.x, acc[1][0]);
            acc[1][1] = fmaf(a.y, bb.y, acc[1][1]);
            acc[1][2] = fmaf(a.y, bb.z, acc[1][2]);
            acc[1][3] = fmaf(a.y, bb.w, acc[1][3]);
            acc[2][0] = fmaf(a.z, bb.x, acc[2][0]);
            acc[2][1] = fmaf(a.z, bb.y, acc[2][1]);
            acc[2][2] = fmaf(a.z, bb.z, acc[2][2]);
            acc[2][3] = fmaf(a.z, bb.w, acc[2][3]);
            acc[3][0] = fmaf(a.w, bb.x, acc[3][0]);
            acc[3][1] = fmaf(a.w, bb.y, acc[3][1]);
            acc[3][2] = fmaf(a.w, bb.z, acc[3][2]);
            acc[3][3] = fmaf(a.w, bb.w, acc[3][3]);
        }
    }

    if (!job) {
        const float4 bv = *(const float4*)(bq + e0 + (tx << 2));
#pragma unroll
        for (int i = 0; i < 4; ++i) {
            float4 o;
            o.x = __builtin_amdgcn_exp2f(C2LOG2E * (acc[i][0] + bv.x));
            o.y = __builtin_amdgcn_exp2f(C2LOG2E * (acc[i][1] + bv.y));
            o.z = __builtin_amdgcn_exp2f(C2LOG2E * (acc[i][2] + bv.z));
            o.w = __builtin_amdgcn_exp2f(C2LOG2E * (acc[i][3] + bv.w));
            *(float4*)(Ea + (size_t)(r0 + (ty << 2) + i) * 512 + e0 + (tx << 2)) = o;
        }
    } else {
        // rows are d, cols are b*S+s. (row>>2) = r0/4 + ty, (row&3) = i.
        float* base = Eu4 + ((size_t)((r0 >> 2) + ty) * 2048 + e0 + (tx << 2)) * 4;
#pragma unroll
        for (int j = 0; j < 4; ++j) {
            float4 o;   // transposed: d-index varies inside the float4
            o.x = __builtin_amdgcn_exp2f(C2LOG2E * acc[0][j]);
            o.y = __builtin_amdgcn_exp2f(C2LOG2E * acc[1][j]);
            o.z = __builtin_amdgcn_exp2f(C2LOG2E * acc[2][j]);
            o.w = __builtin_amdgcn_exp2f(C2LOG2E * acc[3][j]);
            *(float4*)(base + (j << 2)) = o;
        }
    }
}

// ---------------------------------------------------------------------------
// Scorer. Block = 2 waves (128 thr); block tile 4t x 128s (wave: 4t x 64s).
// LDS = As[4][512] + vs[512] = 10KB -> 16 blocks/CU (160KB), 32 waves/CU
// theoretical occupancy with __launch_bounds__(128,8). Main loop's only VMEM
// is the per-lane coalesced Eu4 dwordx4 (distance-1 prefetch); uniform
// operands ride the LDS pipe (broadcast). No main-loop barriers.
// Grid 2048, XCD decode id%8 = (b, s-half): per-XCD L2 set =
// Eu4 slice 512KB + Ea b-slice 1MB.
// ---------------------------------------------------------------------------
__device__ __forceinline__ float grp4(float ax, float ay, float az, float aw,
                                      float4 u, float4 vv, float acc)
{
    const float F0 = fmaf(ax, u.x, 1.0f);
    const float F1 = fmaf(ay, u.y, 1.0f);
    const float F2 = fmaf(az, u.z, 1.0f);
    const float F3 = fmaf(aw, u.w, 1.0f);
    const float g   = F0 * F1;
    const float h   = F2 * F3;
    const float n01 = fmaf(vv.y, F0, vv.x * F1);
    const float n23 = fmaf(vv.w, F2, vv.z * F3);
    const float num = fmaf(n23, g, n01 * h);
    const float den = g * h;
    return fmaf(num, __builtin_amdgcn_rcpf(den), acc);
}

__global__ __launch_bounds__(128, 8) void score_kernel(
    const float* __restrict__ Ea,   // [B*T][512]
    const float* __restrict__ Eu4,  // [(512/4)][2048][4]
    const float* __restrict__ v, float* __restrict__ out)
{
    __shared__ float As[4][512];    // A-tile: 4 t-rows (8KB)
    __shared__ float vs[512];       // v (2KB)
    const int tid  = threadIdx.x;   // 0..127
    const int lane = tid & 63;
    const int w    = tid >> 6;      // 0..1
    const int id   = blockIdx.x;
    const int gg   = id & 7;        // XCD group: (b, s-half)
    const int b    = gg >> 1;
    const int shlf = gg & 1;
    const int k    = id >> 3;       // 0..255
    const int sqtr = k & 1;         // s-quarter within half
    const int tblk = k >> 1;        // 0..127
    const int t0   = tblk << 2;     // 4 t-rows per block
    const int s    = (shlf << 8) + (sqtr << 7) + (w << 6) + lane;

    // sumv = sum_d v[d], butterfly (all lanes get it)
    float p = 0.f;
#pragma unroll
    for (int q = 0; q < 8; ++q) p += v[lane + (q << 6)];
#pragma unroll
    for (int off = 32; off; off >>= 1) p += __shfl_xor(p, off);
    const float sumv = p;

    // Stage A-tile (2048 floats) + v (512 floats) into LDS
    {
        const float* Arow = Ea + (size_t)(b * T_ + t0) * D_;  // 4 consecutive rows
        float* Af = &As[0][0];
#pragma unroll
        for (int pp = 0; pp < 4; ++pp)
            *(float4*)(Af + (tid << 2) + pp * 512) =
                *(const float4*)(Arow + (tid << 2) + pp * 512);
        *(float4*)(vs + (tid << 2)) = *(const float4*)(v + (tid << 2));
    }
    __syncthreads();

    const float* __restrict__ U = Eu4 + ((size_t)b * S_ + s) * 4;  // +32KB per d-group
    float acc0 = 0.f, acc1 = 0.f, acc2 = 0.f, acc3 = 0.f;

#define COMPUTE_DG(DG, UU)                                              \
    {                                                                   \
        const int _o = (DG) << 2;                                       \
        const float4 vv = *(const float4*)&vs[_o];                      \
        const float4 a0 = *(const float4*)&As[0][_o];                   \
        const float4 a1 = *(const float4*)&As[1][_o];                   \
        const float4 a2 = *(const float4*)&As[2][_o];                   \
        const float4 a3 = *(const float4*)&As[3][_o];                   \
        acc0 = grp4(a0.x, a0.y, a0.z, a0.w, UU, vv, acc0);              \
        acc1 = grp4(a1.x, a1.y, a1.z, a1.w, UU, vv, acc1);              \
        acc2 = grp4(a2.x, a2.y, a2.z, a2.w, UU, vv, acc2);              \
        acc3 = grp4(a3.x, a3.y, a3.z, a3.w, UU, vv, acc3);              \
    }

    // distance-1 prefetch: load dg+1 while computing dg
    float4 ucur = *(const float4*)U;
    for (int dg = 0; dg < 127; ++dg) {
        const float4 unext = *(const float4*)(U + (size_t)(dg + 1) * 8192);
        COMPUTE_DG(dg, ucur);
        ucur = unext;
    }
    COMPUTE_DG(127, ucur);
#undef COMPUTE_DG

    float* __restrict__ O = out + (size_t)(b * T_ + t0) * S_ + s;
    O[0 * S_] = sumv - 2.0f * acc0;
    O[1 * S_] = sumv - 2.0f * acc1;
    O[2 * S_] = sumv - 2.0f * acc2;
    O[3 * S_] = sumv - 2.0f * acc3;
}

extern "C" void kernel_launch(void* const* d_in, const int* in_sizes, int n_in,
                              void* d_out, int out_size, void* d_ws, size_t ws_size,
                              hipStream_t stream) {
    const float* h_t = (const float*)d_in[0];  // [4,512,512]
    const float* h_s = (const float*)d_in[1];  // [4,512,512]
    const float* Wq  = (const float*)d_in[2];  // [512,512]
    const float* bq  = (const float*)d_in[3];  // [512]
    const float* Wc  = (const float*)d_in[4];  // [512,512]
    const float* v   = (const float*)d_in[5];  // [512]
    float* out = (float*)d_out;                // [4,512,512]

    float* Ea  = (float*)d_ws;                 // exp2(c*(h_t Wq^T + bq)) [2048][512]
    float* Eu4 = Ea + (size_t)B_ * T_ * D_;    // exp2(c*(h_s Wc^T)), d-interleaved

    gemm_exp_kernel<<<dim3(32, 8, 2), 256, 0, stream>>>(h_t, h_s, Wq, bq, Wc, Ea, Eu4);
    score_kernel<<<dim3(2048, 1, 1), 128, 0, stream>>>(Ea, Eu4, v, out);
}

// Round 8
// 89.568 us; speedup vs baseline: 1.1115x; 1.1115x over previous
//
#include <hip/hip_runtime.h>

// MLPScorer: out[b,t,s] = sum_d v[d] * tanh( (h_t Wq^T + bq)[b,t,d] + (h_s Wc^T)[b,s,d] )
// B=4, T=S=D=512, all f32.
//
// tanh(x) = 1 - 2/(1+e^{2x});  e^{2(a+u)} = ea*eu (separable; precomputed in the
// GEMM epilogue as exp2(c*...), c = 2*log2(e)).
// Scorer: two independent 4-term rational chains ride the lo/hi halves of
// packed-f32 (v_pk_*) registers. Per 8 d's: 14 pk ops + 2 v_rcp.
//   F_i = fma(ea_i, eu_i, 1);  sum_i v_i/F_i = num/den (per chain),
//   num = (v0F1+v1F0)F2F3 + (v2F3+v3F2)F0F1, den = F0F1F2F3.
// Pair-interleaved layout per 8-group: [d0,d4,d1,d5,d2,d6,d3,d7]
// (chain A = d%8<4, chain B = d%8>=4) -> no cross-half shuffles anywhere.
// out = sumv - 2*(accA+accB).

#define B_ 4
#define T_ 512
#define S_ 512
#define D_ 512

typedef float v2f __attribute__((ext_vector_type(2)));

static constexpr float C2LOG2E = 2.8853900817779268f; // 2*log2(e)

// ---------------------------------------------------------------------------
// Dual GEMM + exp2 epilogue, both jobs Out = X * W^T (K = 512), packed-f32
// inner loop (8 v_pk_fma per k instead of 16 v_fma):
//  job0: X=h_t [2048][512], W=Wq  [512][512] -> Ea [2048][512] (+bq), natural
//  job1: X=Wc  [512][512],  W=h_s [2048][512] -> Eu8, pair-interleaved:
//        Eu8[ (g*2048 + col)*8 + 2j + p ] = exp2(c*uh[d]), d = g*8 + j + 4p
// ---------------------------------------------------------------------------
__global__ __launch_bounds__(256) void gemm_exp_kernel(
    const float* __restrict__ Ht, const float* __restrict__ Hs,
    const float* __restrict__ Wq, const float* __restrict__ bq,
    const float* __restrict__ Wc,
    float* __restrict__ Ea, float* __restrict__ Eu8)
{
    __shared__ float Xs[32][68];   // [k][row]
    __shared__ float Ws[32][68];   // [k][col]
    const int job = blockIdx.z;
    const float* __restrict__ X = job ? Wc : Ht;
    const float* __restrict__ W = job ? Hs : Wq;
    const int r0 = (job ? blockIdx.y : blockIdx.x) * 64;   // X-row block
    const int e0 = (job ? blockIdx.x : blockIdx.y) * 64;   // W-row (out col) block

    const int tid = threadIdx.x;
    const int tx  = tid & 15;      // col group (4 cols)
    const int ty  = tid >> 4;      // row group (4 rows)
    const int li  = tid >> 3;          // 0..31 staging row
    const int lk  = (tid & 7) << 2;    // 0,4,...,28 staging k

    v2f acc2[4][2] = {};           // [row][col-pair], packed f32

    for (int k0 = 0; k0 < D_; k0 += 32) {
        const float4 x0 = *(const float4*)(X + (size_t)(r0 + li)      * D_ + k0 + lk);
        const float4 x1 = *(const float4*)(X + (size_t)(r0 + li + 32) * D_ + k0 + lk);
        const float4 w0 = *(const float4*)(W + (size_t)(e0 + li)      * D_ + k0 + lk);
        const float4 w1 = *(const float4*)(W + (size_t)(e0 + li + 32) * D_ + k0 + lk);
        __syncthreads();   // protect previous chunk's LDS reads
        Xs[lk+0][li] = x0.x; Xs[lk+1][li] = x0.y; Xs[lk+2][li] = x0.z; Xs[lk+3][li] = x0.w;
        Xs[lk+0][li+32] = x1.x; Xs[lk+1][li+32] = x1.y; Xs[lk+2][li+32] = x1.z; Xs[lk+3][li+32] = x1.w;
        Ws[lk+0][li] = w0.x; Ws[lk+1][li] = w0.y; Ws[lk+2][li] = w0.z; Ws[lk+3][li] = w0.w;
        Ws[lk+0][li+32] = w1.x; Ws[lk+1][li+32] = w1.y; Ws[lk+2][li+32] = w1.z; Ws[lk+3][li+32] = w1.w;
        __syncthreads();
#pragma unroll
        for (int k = 0; k < 32; ++k) {
            const float4 a  = *(const float4*)&Xs[k][ty << 2];
            const float4 bb = *(const float4*)&Ws[k][tx << 2];
            const v2f b0 = {bb.x, bb.y};
            const v2f b1 = {bb.z, bb.w};
            const v2f ax = {a.x, a.x};
            const v2f ay = {a.y, a.y};
            const v2f az = {a.z, a.z};
            const v2f aw = {a.w, a.w};
            acc2[0][0] = __builtin_elementwise_fma(ax, b0, acc2[0][0]);
            acc2[0][1] = __builtin_elementwise_fma(ax, b1, acc2[0][1]);
            acc2[1][0] = __builtin_elementwise_fma(ay, b0, acc2[1][0]);
            acc2[1][1] = __builtin_elementwise_fma(ay, b1, acc2[1][1]);
            acc2[2][0] = __builtin_elementwise_fma(az, b0, acc2[2][0]);
            acc2[2][1] = __builtin_elementwise_fma(az, b1, acc2[2][1]);
            acc2[3][0] = __builtin_elementwise_fma(aw, b0, acc2[3][0]);
            acc2[3][1] = __builtin_elementwise_fma(aw, b1, acc2[3][1]);
        }
    }

    if (!job) {
        const float4 bv = *(const float4*)(bq + e0 + (tx << 2));
#pragma unroll
        for (int i = 0; i < 4; ++i) {
            float4 o;
            o.x = __builtin_amdgcn_exp2f(C2LOG2E * (acc2[i][0].x + bv.x));
            o.y = __builtin_amdgcn_exp2f(C2LOG2E * (acc2[i][0].y + bv.y));
            o.z = __builtin_amdgcn_exp2f(C2LOG2E * (acc2[i][1].x + bv.z));
            o.w = __builtin_amdgcn_exp2f(C2LOG2E * (acc2[i][1].y + bv.w));
            *(float4*)(Ea + (size_t)(r0 + (ty << 2) + i) * 512 + e0 + (tx << 2)) = o;
        }
    } else {
        // thread owns d-rows r0+4ty+i (i=0..3); 8-group g, parity p.
        const int dq  = (r0 >> 2) + ty;   // d-quad index
        const int g8  = dq >> 1;
        const int par = dq & 1;
        float* base = Eu8 + ((size_t)g8 * 2048 + e0 + (tx << 2)) * 8 + par;
#pragma unroll
        for (int j = 0; j < 4; ++j) {     // output column e0+tx*4+j
            const float c0 = (j & 2) ? acc2[0][1][j & 1] : acc2[0][0][j & 1];
            const float c1 = (j & 2) ? acc2[1][1][j & 1] : acc2[1][0][j & 1];
            const float c2 = (j & 2) ? acc2[2][1][j & 1] : acc2[2][0][j & 1];
            const float c3 = (j & 2) ? acc2[3][1][j & 1] : acc2[3][0][j & 1];
            base[(size_t)j * 8 + 0] = __builtin_amdgcn_exp2f(C2LOG2E * c0);
            base[(size_t)j * 8 + 2] = __builtin_amdgcn_exp2f(C2LOG2E * c1);
            base[(size_t)j * 8 + 4] = __builtin_amdgcn_exp2f(C2LOG2E * c2);
            base[(size_t)j * 8 + 6] = __builtin_amdgcn_exp2f(C2LOG2E * c3);
        }
    }
}

// ---------------------------------------------------------------------------
// Scorer. Block = 2 waves (128 thr); tile 4t x 128s (wave: 4t x 64s, lane=s).
// A-tile + v staged in LDS pair-interleaved (one-time); main loop per iter
// handles 8 d's: two coalesced dwordx4 of Eu8 (distance-1 prefetch), uniform
// LDS b128 broadcasts, all math packed f32 (v_pk_*), 2 rcp per 8d-chain-pair.
// Grid 2048, XCD decode id%8 = (b, s-half).
// ---------------------------------------------------------------------------
__global__ __launch_bounds__(128, 6) void score_kernel(
    const float* __restrict__ Ea,   // [B*T][512] natural
    const float* __restrict__ Eu8,  // [(512/8)][2048][8] pair-interleaved
    const float* __restrict__ v, float* __restrict__ out)
{
    __shared__ float As[4][512];    // A-tile, pair-interleaved per 8-group
    __shared__ float vs[512];       // v, pair-interleaved
    const int tid  = threadIdx.x;   // 0..127
    const int lane = tid & 63;
    const int w    = tid >> 6;      // 0..1
    const int id   = blockIdx.x;
    const int gg   = id & 7;        // XCD group: (b, s-half)
    const int b    = gg >> 1;
    const int shlf = gg & 1;
    const int k    = id >> 3;       // 0..255
    const int sqtr = k & 1;
    const int tblk = k >> 1;        // 0..127
    const int t0   = tblk << 2;
    const int s    = (shlf << 8) + (sqtr << 7) + (w << 6) + lane;

    // sumv = sum_d v[d], butterfly (all lanes get it)
    float p = 0.f;
#pragma unroll
    for (int q = 0; q < 8; ++q) p += v[lane + (q << 6)];
#pragma unroll
    for (int off = 32; off; off >>= 1) p += __shfl_xor(p, off);
    const float sumv = p;

    // Stage A-tile + v into LDS, pair-interleaving each 8-group:
    // src d = 4*tid + k  ->  dst = (tid>>1)*8 + 2k + (tid&1)
    {
        const float* Arow = Ea + (size_t)(b * T_ + t0) * D_;  // 4 consecutive rows
#pragma unroll
        for (int pp = 0; pp < 4; ++pp) {
            const float4 q = *(const float4*)(Arow + pp * 512 + (tid << 2));
            float* dst = &As[pp][((tid >> 1) << 3) + (tid & 1)];
            dst[0] = q.x; dst[2] = q.y; dst[4] = q.z; dst[6] = q.w;
        }
        const float4 q = *(const float4*)(v + (tid << 2));
        float* dst = &vs[((tid >> 1) << 3) + (tid & 1)];
        dst[0] = q.x; dst[2] = q.y; dst[4] = q.z; dst[6] = q.w;
    }
    __syncthreads();

    const float* __restrict__ U = Eu8 + ((size_t)b * S_ + s) * 8;  // +64KB per 8-group
    const v2f vone = {1.0f, 1.0f};
    v2f acc0 = {}, acc1 = {}, acc2v = {}, acc3 = {};

#define GRP8(ROW, ACC)                                                  \
    {                                                                   \
        const float4 q0 = *(const float4*)&ROW[_o];                     \
        const float4 q1 = *(const float4*)&ROW[_o + 4];                 \
        const v2f a0 = {q0.x, q0.y}, a1 = {q0.z, q0.w};                 \
        const v2f a2 = {q1.x, q1.y}, a3 = {q1.z, q1.w};                 \
        const v2f F0 = __builtin_elementwise_fma(a0, u0, vone);         \
        const v2f F1 = __builtin_elementwise_fma(a1, u1, vone);         \
        const v2f F2 = __builtin_elementwise_fma(a2, u2, vone);         \
        const v2f F3 = __builtin_elementwise_fma(a3, u3, vone);         \
        const v2f g   = F0 * F1;                                        \
        const v2f h   = F2 * F3;                                        \
        const v2f n01 = __builtin_elementwise_fma(vp1, F0, vp0 * F1);   \
        const v2f n23 = __builtin_elementwise_fma(vp3, F2, vp2 * F3);   \
        const v2f num = __builtin_elementwise_fma(n23, g, n01 * h);     \
        const v2f den = g * h;                                          \
        v2f r;                                                          \
        r.x = __builtin_amdgcn_rcpf(den.x);                             \
        r.y = __builtin_amdgcn_rcpf(den.y);                             \
        ACC = __builtin_elementwise_fma(num, r, ACC);                   \
    }

#define COMPUTE_DG(DG, U0, U1)                                          \
    {                                                                   \
        const int _o = (DG) << 3;                                       \
        const v2f u0 = {U0.x, U0.y}, u1 = {U0.z, U0.w};                 \
        const v2f u2 = {U1.x, U1.y}, u3 = {U1.z, U1.w};                 \
        const float4 vq0 = *(const float4*)&vs[_o];                     \
        const float4 vq1 = *(const float4*)&vs[_o + 4];                 \
        const v2f vp0 = {vq0.x, vq0.y}, vp1 = {vq0.z, vq0.w};           \
        const v2f vp2 = {vq1.x, vq1.y}, vp3 = {vq1.z, vq1.w};           \
        GRP8(As[0], acc0)                                               \
        GRP8(As[1], acc1)                                               \
        GRP8(As[2], acc2v)                                              \
        GRP8(As[3], acc3)                                               \
    }

    // distance-1 prefetch: load 8-group dg+1 while computing dg
    float4 uc0 = *(const float4*)U;
    float4 uc1 = *(const float4*)(U + 4);
    for (int dg = 0; dg < 63; ++dg) {
        const float* nxt = U + (size_t)(dg + 1) * 16384;
        const float4 un0 = *(const float4*)nxt;
        const float4 un1 = *(const float4*)(nxt + 4);
        COMPUTE_DG(dg, uc0, uc1);
        uc0 = un0; uc1 = un1;
    }
    COMPUTE_DG(63, uc0, uc1);
#undef COMPUTE_DG
#undef GRP8

    float* __restrict__ O = out + (size_t)(b * T_ + t0) * S_ + s;
    O[0 * S_] = sumv - 2.0f * (acc0.x + acc0.y);
    O[1 * S_] = sumv - 2.0f * (acc1.x + acc1.y);
    O[2 * S_] = sumv - 2.0f * (acc2v.x + acc2v.y);
    O[3 * S_] = sumv - 2.0f * (acc3.x + acc3.y);
}

extern "C" void kernel_launch(void* const* d_in, const int* in_sizes, int n_in,
                              void* d_out, int out_size, void* d_ws, size_t ws_size,
                              hipStream_t stream) {
    const float* h_t = (const float*)d_in[0];  // [4,512,512]
    const float* h_s = (const float*)d_in[1];  // [4,512,512]
    const float* Wq  = (const float*)d_in[2];  // [512,512]
    const float* bq  = (const float*)d_in[3];  // [512]
    const float* Wc  = (const float*)d_in[4];  // [512,512]
    const float* v   = (const float*)d_in[5];  // [512]
    float* out = (float*)d_out;                // [4,512,512]

    float* Ea  = (float*)d_ws;                 // exp2(c*(h_t Wq^T + bq)) [2048][512]
    float* Eu8 = Ea + (size_t)B_ * T_ * D_;    // exp2(c*(h_s Wc^T)), pair-interleaved

    gemm_exp_kernel<<<dim3(32, 8, 2), 256, 0, stream>>>(h_t, h_s, Wq, bq, Wc, Ea, Eu8);
    score_kernel<<<dim3(2048, 1, 1), 128, 0, stream>>>(Ea, Eu8, v, out);
}